// Round 4
// baseline (469.427 us; speedup 1.0000x reference)
//
#include <hip/hip_runtime.h>

// Problem constants
#define NB 4096   // batches
#define NT 64     // tokens
#define ND 128    // d_model
#define NTD 8192  // NT*ND

using bf16x8 = __attribute__((ext_vector_type(8))) short;
using s16x4  = __attribute__((ext_vector_type(4))) short;
using f32x4  = __attribute__((ext_vector_type(4))) float;

__device__ __forceinline__ short f2bf(float x) {
  union { float f; unsigned u; } v; v.f = x;
  unsigned r = (v.u + 0x7FFFu + ((v.u >> 16) & 1u)) >> 16;
  return (short)r;
}
__device__ __forceinline__ float bf2f(short h) {
  union { unsigned u; float f; } v; v.u = ((unsigned)(unsigned short)h) << 16;
  return v.f;
}

// ---------------------------------------------------------------------------
// Kernel: convert W1, W2 to bf16
// ---------------------------------------------------------------------------
__global__ __launch_bounds__(256) void k_cvt(const float* __restrict__ W1,
                                             const float* __restrict__ W2,
                                             short* __restrict__ W1b,
                                             short* __restrict__ W2b) {
  int idx = blockIdx.x * 256 + threadIdx.x;  // 0..524287 float4s (2 x 1M floats)
  const float4* src; short* dst;
  if (idx < 262144) { src = (const float4*)W1; dst = W1b; }
  else { idx -= 262144; src = (const float4*)W2; dst = W2b; }
  float4 v = src[idx];
  s16x4 p = { f2bf(v.x), f2bf(v.y), f2bf(v.z), f2bf(v.w) };
  *(s16x4*)&dst[4 * idx] = p;
}

// ---------------------------------------------------------------------------
// Kernel: per-batch attention.  ydot = softmax(X X^T / sqrt(D)) X + X  (bf16)
// Also emits Xbf = bf16(X) for gemm1.
// One block (4 waves) per batch.
// ---------------------------------------------------------------------------
#define LDX 136  // padded row stride (shorts); 272B = 17*16
#define LDT 72   // XT row stride (shorts); 144B = 9*16
#define LDP 72
#define LDO 136  // epilogue bounce stride (shorts), aliases XT

__global__ __launch_bounds__(256) void k_attn(const float* __restrict__ X,
                                              short* __restrict__ ydot,
                                              short* __restrict__ Xbf) {
  __shared__ short Xl[NT * LDX];    // 17408 B: X[b] row-major (token x d)
  __shared__ short XT[ND * LDT];    // 18432 B: X[b]^T (d x token); reused as Ol
  __shared__ short Pl[4][16 * LDP]; // 9216 B: per-wave softmax tiles

  const int b = blockIdx.x;
  const int tid = threadIdx.x;
  const float4* X4 = (const float4*)(X + (size_t)b * NTD);
  short* xb = Xbf + (size_t)b * NTD;

  // Phase 1: global fp32 -> Xl bf16 (row-major) + Xbf global (coalesced 8B)
  for (int it = 0; it < 8; ++it) {
    int idx = tid + 256 * it;        // 0..2047 float4s
    int r = idx >> 5;                // 32 float4 per row
    int c4 = idx & 31;
    float4 v = X4[idx];
    s16x4 p = { f2bf(v.x), f2bf(v.y), f2bf(v.z), f2bf(v.w) };
    *(s16x4*)&Xl[r * LDX + 4 * c4] = p;
    *(s16x4*)&xb[4 * idx] = p;
  }
  __syncthreads();

  // Phase 2: build XT[d][t] = Xl[t][d].  Thread: d = tid>>1, 32 tokens.
  // Reads 2B ~4-way, writes 8B ~4-way (vs 16-way scatter before).
  {
    int d = tid >> 1;
    int t0 = (tid & 1) * 32;
    for (int j = 0; j < 8; ++j) {
      s16x4 p;
      for (int e = 0; e < 4; ++e) p[e] = Xl[(t0 + 4 * j + e) * LDX + d];
      *(s16x4*)&XT[d * LDT + t0 + 4 * j] = p;
    }
  }
  __syncthreads();

  const int w = tid >> 6;
  const int l = tid & 63;
  const int g = l >> 4;
  const int ln = l & 15;

  // S = X X^T / sqrt(D) : wave w computes rows [16w,16w+16), 4 col-tiles
  f32x4 S[4];
  for (int tj = 0; tj < 4; ++tj) S[tj] = f32x4{0.f, 0.f, 0.f, 0.f};
  for (int kk = 0; kk < 4; ++kk) {
    bf16x8 a = *(const bf16x8*)&Xl[(16 * w + ln) * LDX + 32 * kk + 8 * g];
    for (int tj = 0; tj < 4; ++tj) {
      bf16x8 bb = *(const bf16x8*)&Xl[(16 * tj + ln) * LDX + 32 * kk + 8 * g];
      S[tj] = __builtin_amdgcn_mfma_f32_16x16x32_bf16(a, bb, S[tj], 0, 0, 0);
    }
  }

  // Wave-parallel softmax.  C layout: row = 4g+i (local), col = 16*tj + ln.
  const float scale = 0.08838834764831845f;  // 1/sqrt(128)
  float li[4];
  for (int i = 0; i < 4; ++i) {
    float p[4];
    float mx = -1e30f;
    for (int tj = 0; tj < 4; ++tj) {
      float s = S[tj][i] * scale;
      p[tj] = s;
      mx = fmaxf(mx, s);
    }
    for (int msk = 1; msk < 16; msk <<= 1) mx = fmaxf(mx, __shfl_xor(mx, msk));
    float sum = 0.f;
    for (int tj = 0; tj < 4; ++tj) {
      float e = __expf(p[tj] - mx);
      p[tj] = e;
      sum += e;
    }
    for (int msk = 1; msk < 16; msk <<= 1) sum += __shfl_xor(sum, msk);
    li[i] = 1.0f / sum;
    for (int tj = 0; tj < 4; ++tj)
      Pl[w][(4 * g + i) * LDP + 16 * tj + ln] = f2bf(p[tj]);
  }
  // Pl[w] is wave-private: same-wave DS RAW is ordered by lgkmcnt, no barrier.

  // PV: X_dot rows [16w,16w+16) = P (16x64) @ X (64x128); + X residual
  bf16x8 a0 = *(const bf16x8*)&Pl[w][ln * LDP + 8 * g];
  bf16x8 a1 = *(const bf16x8*)&Pl[w][ln * LDP + 32 + 8 * g];
  f32x4 av[8];
  for (int c = 0; c < 8; ++c) {
    f32x4 acc = f32x4{0.f, 0.f, 0.f, 0.f};
    bf16x8 b0 = *(const bf16x8*)&XT[(16 * c + ln) * LDT + 8 * g];
    bf16x8 b1 = *(const bf16x8*)&XT[(16 * c + ln) * LDT + 32 + 8 * g];
    acc = __builtin_amdgcn_mfma_f32_16x16x32_bf16(a0, b0, acc, 0, 0, 0);
    acc = __builtin_amdgcn_mfma_f32_16x16x32_bf16(a1, b1, acc, 0, 0, 0);
    av[c] = acc;
  }
  // scale + residual (reads Xl only)
  for (int c = 0; c < 8; ++c)
    for (int i = 0; i < 4; ++i) {
      int row = 16 * w + 4 * g + i;
      int col = 16 * c + ln;
      av[c][i] = av[c][i] * li[i] + bf2f(Xl[row * LDX + col]);
    }
  __syncthreads();  // all waves done reading XT

  // Bounce through LDS (Ol aliases XT) for coalesced 16B global stores
  short* Ol = XT;
  for (int c = 0; c < 8; ++c)
    for (int i = 0; i < 4; ++i) {
      int row = 16 * w + 4 * g + i;
      int col = 16 * c + ln;
      Ol[row * LDO + col] = f2bf(av[c][i]);
    }
  __syncthreads();
  {
    int row = tid >> 2, seg = tid & 3;
    short* yrow = ydot + (size_t)b * NTD + row * ND + seg * 32;
    for (int j = 0; j < 4; ++j)
      *(bf16x8*)&yrow[8 * j] = *(const bf16x8*)&Ol[row * LDO + seg * 32 + 8 * j];
  }
}

// ---------------------------------------------------------------------------
// Kernel: GEMM1 partials: hpart[kz] = Xbf @ W1^T over K-chunk kz.
// grid (64 Mtiles, 4 Ksplits), BM=64, BN=128, K-chunk 2048 (32 steps of BK=64)
// No atomics: 4 private partial buffers summed by k_hact.
// ---------------------------------------------------------------------------
#define LDA1 72  // BK=64 + 8 pad shorts; 144B rows

__global__ __launch_bounds__(256) void k_gemm1(const short* __restrict__ Xbf,
                                               const short* __restrict__ W1b,
                                               float* __restrict__ hpart) {
  __shared__ short Al[64 * LDA1];   // 9216 B
  __shared__ short Bl[128 * LDA1];  // 18432 B
  const int mt = blockIdx.x;
  const int kz = blockIdx.y;
  const int tid = threadIdx.x;
  const int w = tid >> 6, l = tid & 63, g = l >> 4, ln = l & 15;

  f32x4 acc[8];
  for (int c = 0; c < 8; ++c) acc[c] = f32x4{0.f, 0.f, 0.f, 0.f};

  for (int s = 0; s < 32; ++s) {
    int kb = kz * 2048 + s * 64;
    // stage A: 64 rows x 64 k (bf16), 2 x bf16x8 per thread
    for (int it = 0; it < 2; ++it) {
      int idx = tid + 256 * it;      // 0..511
      int r = idx >> 3, f = idx & 7;
      *(bf16x8*)&Al[r * LDA1 + 8 * f] =
          *(const bf16x8*)&Xbf[(size_t)(mt * 64 + r) * NTD + kb + 8 * f];
    }
    // stage B: 128 rows x 64 k, 4 x bf16x8 per thread
    for (int it = 0; it < 4; ++it) {
      int idx = tid + 256 * it;      // 0..1023
      int n = idx >> 3, f = idx & 7;
      *(bf16x8*)&Bl[n * LDA1 + 8 * f] =
          *(const bf16x8*)&W1b[(size_t)n * NTD + kb + 8 * f];
    }
    __syncthreads();
    for (int kk = 0; kk < 2; ++kk) {
      bf16x8 a = *(const bf16x8*)&Al[(16 * w + ln) * LDA1 + 32 * kk + 8 * g];
      for (int c = 0; c < 8; ++c) {
        bf16x8 bb = *(const bf16x8*)&Bl[(16 * c + ln) * LDA1 + 32 * kk + 8 * g];
        acc[c] = __builtin_amdgcn_mfma_f32_16x16x32_bf16(a, bb, acc[c], 0, 0, 0);
      }
    }
    __syncthreads();
  }
  float* hp = hpart + (size_t)kz * (NB * ND);
  for (int c = 0; c < 8; ++c)
    for (int i = 0; i < 4; ++i) {
      int m = mt * 64 + 16 * w + 4 * g + i;
      int n = 16 * c + ln;
      hp[m * ND + n] = acc[c][i];
    }
}

// ---------------------------------------------------------------------------
// Kernel: hb = bf16(relu(sum_kz hpart + b1))
// ---------------------------------------------------------------------------
__global__ __launch_bounds__(256) void k_hact(const float* __restrict__ hpart,
                                              const float* __restrict__ b1,
                                              short* __restrict__ hb) {
  int idx = blockIdx.x * 256 + threadIdx.x;  // 0..131071 float4s
  const float4* p0 = (const float4*)hpart;
  float4 v = p0[idx];
  float4 v1 = p0[idx + 131072];
  float4 v2 = p0[idx + 262144];
  float4 v3 = p0[idx + 393216];
  float4 bb = ((const float4*)b1)[idx & 31];
  s16x4 r;
  r[0] = f2bf(fmaxf(v.x + v1.x + v2.x + v3.x + bb.x, 0.f));
  r[1] = f2bf(fmaxf(v.y + v1.y + v2.y + v3.y + bb.y, 0.f));
  r[2] = f2bf(fmaxf(v.z + v1.z + v2.z + v3.z + bb.z, 0.f));
  r[3] = f2bf(fmaxf(v.w + v1.w + v2.w + v3.w + bb.w, 0.f));
  *(s16x4*)&hb[4 * idx] = r;
}

// ---------------------------------------------------------------------------
// Kernel: GEMM2 + residual + LayerNorm.
// out = LN(h @ W2^T + b2 + ydot) * gamma + beta
// grid (64 Mtiles, 64 Ntiles), BM=64, BN=128, K=128 (4 MFMA steps)
// BN=128 == one full LN row per output-tile row.  Coalesced stores via
// an LDS bounce that reuses the Bl region.
// ---------------------------------------------------------------------------
#define LDK 136
#define LDO2 132  // fp32 bounce stride (floats); 528B = 33*16

__global__ __launch_bounds__(256) void k_gemm2(const short* __restrict__ hb,
                                               const short* __restrict__ W2b,
                                               const short* __restrict__ ydot,
                                               const float* __restrict__ b2,
                                               const float* __restrict__ gamma,
                                               const float* __restrict__ beta,
                                               float* __restrict__ out) {
  __shared__ short Al[64 * LDK];    // 17408 B
  __shared__ short Bl[128 * LDK];   // 34816 B (>= 64*132*4 = 33792 bounce)
  __shared__ short Yl[64 * LDK];    // 17408 B
  __shared__ float g_s[128], be_s[128], b2_s[128];

  const int mt = blockIdx.x, nt = blockIdx.y;
  const int tid = threadIdx.x;

  for (int it = 0; it < 4; ++it) {     // A: h tile 64x128
    int idx = tid + 256 * it;          // 0..1023
    int r = idx >> 4, f = idx & 15;
    *(bf16x8*)&Al[r * LDK + 8 * f] =
        *(const bf16x8*)&hb[(size_t)(mt * 64 + r) * ND + 8 * f];
  }
  for (int it = 0; it < 8; ++it) {     // B: W2 tile 128x128
    int idx = tid + 256 * it;          // 0..2047
    int n = idx >> 4, f = idx & 15;
    *(bf16x8*)&Bl[n * LDK + 8 * f] =
        *(const bf16x8*)&W2b[(size_t)(nt * 128 + n) * ND + 8 * f];
  }
  for (int it = 0; it < 4; ++it) {     // ydot tile 64x128
    int idx = tid + 256 * it;
    int r = idx >> 4, f = idx & 15;
    *(bf16x8*)&Yl[r * LDK + 8 * f] =
        *(const bf16x8*)&ydot[(size_t)(mt * 64 + r) * NTD + nt * 128 + 8 * f];
  }
  if (tid < 128) {
    g_s[tid] = gamma[tid];
    be_s[tid] = beta[tid];
    b2_s[tid] = b2[nt * 128 + tid];
  }
  __syncthreads();

  const int w = tid >> 6, l = tid & 63, g = l >> 4, ln = l & 15;
  f32x4 acc[8];
  for (int c = 0; c < 8; ++c) acc[c] = f32x4{0.f, 0.f, 0.f, 0.f};
  for (int kk = 0; kk < 4; ++kk) {
    bf16x8 a = *(const bf16x8*)&Al[(16 * w + ln) * LDK + 32 * kk + 8 * g];
    for (int c = 0; c < 8; ++c) {
      bf16x8 bb = *(const bf16x8*)&Bl[(16 * c + ln) * LDK + 32 * kk + 8 * g];
      acc[c] = __builtin_amdgcn_mfma_f32_16x16x32_bf16(a, bb, acc[c], 0, 0, 0);
    }
  }

  // Epilogue: +b2 +ydot, LayerNorm across the 128 cols of each row.
  float o[4][8];
#pragma unroll
  for (int i = 0; i < 4; ++i) {
    int lr = 16 * w + 4 * g + i;   // local row (batch within tile)
    float v[8];
    float s = 0.f;
#pragma unroll
    for (int c = 0; c < 8; ++c) {
      int d = 16 * c + ln;
      v[c] = acc[c][i] + b2_s[d] + bf2f(Yl[lr * LDK + d]);
      s += v[c];
    }
    for (int msk = 1; msk < 16; msk <<= 1) s += __shfl_xor(s, msk);
    float mu = s * (1.f / 128.f);
    float s2 = 0.f;
#pragma unroll
    for (int c = 0; c < 8; ++c) { float d2 = v[c] - mu; s2 += d2 * d2; }
    for (int msk = 1; msk < 16; msk <<= 1) s2 += __shfl_xor(s2, msk);
    float rstd = rsqrtf(s2 * (1.f / 128.f) + 1e-5f);
#pragma unroll
    for (int c = 0; c < 8; ++c) {
      int d = 16 * c + ln;
      o[i][c] = (v[c] - mu) * rstd * g_s[d] + be_s[d];
    }
  }
  __syncthreads();  // all waves done reading Bl

  float* Ob = (float*)Bl;  // bounce, 64 x LDO2 floats
#pragma unroll
  for (int i = 0; i < 4; ++i) {
    int lr = 16 * w + 4 * g + i;
#pragma unroll
    for (int c = 0; c < 8; ++c) Ob[lr * LDO2 + 16 * c + ln] = o[i][c];
  }
  __syncthreads();
  {
    int row = tid >> 2, seg = tid & 3;
    float* drow = out + (size_t)(mt * 64 + row) * NTD + nt * 128 + seg * 32;
    for (int j = 0; j < 8; ++j)
      *(float4*)&drow[4 * j] = *(const float4*)&Ob[row * LDO2 + seg * 32 + 4 * j];
  }
}

// ---------------------------------------------------------------------------
extern "C" void kernel_launch(void* const* d_in, const int* in_sizes, int n_in,
                              void* d_out, int out_size, void* d_ws, size_t ws_size,
                              hipStream_t stream) {
  const float* X     = (const float*)d_in[0];
  const float* W1    = (const float*)d_in[1];
  const float* b1    = (const float*)d_in[2];
  const float* W2    = (const float*)d_in[3];
  const float* b2    = (const float*)d_in[4];
  const float* gamma = (const float*)d_in[5];
  const float* beta  = (const float*)d_in[6];
  float* out = (float*)d_out;

  char* ws = (char*)d_ws;
  short* ydot = (short*)ws;                                  // 64 MB
  short* Xbf  = (short*)(ws + (64u << 20));                  // 64 MB
  short* W1b  = (short*)(ws + (128u << 20));                 // 2 MB
  short* W2b  = (short*)(ws + (130u << 20));                 // 2 MB
  float* hpart = (float*)(ws + (132u << 20));                // 8 MB (4 x 2MB)
  short* hb   = (short*)(ws + (140u << 20));                 // 1 MB

  k_cvt<<<2048, 256, 0, stream>>>(W1, W2, W1b, W2b);
  k_attn<<<NB, 256, 0, stream>>>(X, ydot, Xbf);
  k_gemm1<<<dim3(64, 4), 256, 0, stream>>>(Xbf, W1b, hpart);
  k_hact<<<512, 256, 0, stream>>>(hpart, b1, hb);
  k_gemm2<<<dim3(64, 64), 256, 0, stream>>>(hb, W2b, ydot, b2, gamma, beta, out);
}